// Round 11
// baseline (378.631 us; speedup 1.0000x reference)
//
#include <hip/hip_runtime.h>

// B=16, C=1, H=512, W=640
#define BB 16
#define HH 512
#define WW 640
constexpr int HW = HH * WW;

#define WT 64
#define HT 16
#define RP 4                 // center rows per thread
#define PAD 4
#define LW (WT + 2*PAD)      // 72
#define LH (HT + PAD)        // 20 (bottom halo only; pair symmetry needs no top)
#define LHW (LH * LW)        // 1440
#define NIT ((LHW + 255) / 256)  // 6
#define GX (WW / WT)         // 10
#define GY (HH / HT)         // 32

constexpr float HALO  = 1.0e6f;                       // OOB fill -> c=0
constexpr float INV_N = 1.0f / (16.0f * 327680.0f);   // 1/(B*H*W)
constexpr float K_INT = (2.0f / 81.0f) * INV_N;       // interior pair weight

__device__ __forceinline__ float fast_rcp(float x) {
    return __builtin_amdgcn_rcpf(x);
}

// one tap, all 64 lanes: masks stay in SGPRs (scalar pipe), acc is wave-uniform
__device__ __forceinline__ void tap_scalar(float ex, float tq, float eh, float th,
                                           float el, float tl, int& acc)
{
    unsigned long long m1, m2;
    int c1, c2;
    asm("v_cmp_gt_f32 %[m1], %[ex], %[eh]\n\t"
        "v_cmp_gt_f32 %[m2], %[tq], %[th]\n\t"
        "s_xor_b64 %[m1], %[m1], %[m2]\n\t"
        "s_bcnt1_i32_b64 %[c1], %[m1]\n\t"
        "v_cmp_lt_f32 %[m1], %[ex], %[el]\n\t"
        "v_cmp_lt_f32 %[m2], %[tq], %[tl]\n\t"
        "s_xor_b64 %[m1], %[m1], %[m2]\n\t"
        "s_bcnt1_i32_b64 %[c2], %[m1]\n\t"
        "s_add_i32 %[acc], %[acc], %[c1]\n\t"
        "s_add_i32 %[acc], %[acc], %[c2]"
        : [m1]"=&s"(m1), [m2]"=&s"(m2), [c1]"=&s"(c1), [c2]"=&s"(c2),
          [acc]"+s"(acc)
        : [ex]"v"(ex), [tq]"v"(tq), [eh]"v"(eh), [th]"v"(th),
          [el]"v"(el), [tl]"v"(tl)
        : "scc");
}

__global__ __launch_bounds__(1)
void zero_kernel(float* __restrict__ out) { out[0] = 0.0f; }

// ============ interior: unguarded staging, scalar-pipe census, atomicAdd =====
__global__ __launch_bounds__(256)
void interior_kernel(const float* __restrict__ disp0,
                     const float* __restrict__ im,
                     const float* __restrict__ pattern,
                     float* __restrict__ out)       // [val, proj...]
{
    __shared__ float2 sm[LHW];

    const int bx = blockIdx.x + 1;   // 1..GX-2
    const int by = blockIdx.y + 1;   // 1..GY-2
    const int b  = blockIdx.z;
    const int tx = threadIdx.x, rg = threadIdx.y;
    const int tid = rg * 64 + tx;

    const float* db = disp0 + (size_t)b * HW;
    const float* ib = im    + (size_t)b * HW;
    float* proj = out + 1 + (size_t)b * HW;

    const int gh0 = by * HT;          // rows 16..499: all in-bounds
    const int gw0 = bx * WT - PAD;    // cols 60..579: all in-bounds

    // phase 1: batched coalesced loads (independent -> ILP), no guards
    float dv[NIT], tv[NIT];
    #pragma unroll
    for (int it = 0; it < NIT; ++it) {
        int i = tid + it * 256;
        if (i < LHW) {
            int lh = i / LW, lw = i - lh * LW;
            int g = (gh0 + lh) * WW + (gw0 + lw);
            dv[it] = db[g];
            tv[it] = ib[g];
        }
    }
    // phase 2: 3-channel pattern gathers (L2-hot) + lerp, write LDS + proj
    #pragma unroll
    for (int it = 0; it < NIT; ++it) {
        int i = tid + it * 256;
        if (i < LHW) {
            int lh = i / LW, lw = i - lh * LW;
            int gh = gh0 + lh, gw = gw0 + lw;
            int g = gh * WW + gw;
            float x = fminf(fmaxf((float)gw - dv[it], 0.0f), (float)(WW - 1));
            int   x0 = (int)x;
            int   x1 = min(x0 + 1, WW - 1);
            float w  = x - (float)x0;
            const float* pr = pattern + gh * WW;
            float p0 = (pr[x0] + pr[HW + x0] + pr[2*HW + x0]) * (1.0f/3.0f);
            float p1 = (pr[x1] + pr[HW + x1] + pr[2*HW + x1]) * (1.0f/3.0f);
            float ev = p0 * (1.0f - w) + p1 * w;
            if ((lh < HT) & (lw >= PAD) & (lw < PAD + WT))
                proj[g] = ev;
            sm[i] = make_float2(ev, tv[it]);
        }
    }
    __syncthreads();

    // census: 40 forward taps per center, masks on the scalar pipe
    float ehi[RP], elo[RP], thi[RP], tlo[RP];
    #pragma unroll
    for (int p = 0; p < RP; ++p) {
        float2 c = sm[(rg * RP + p) * LW + tx + PAD];
        ehi[p] = c.x + 0.5f;  elo[p] = c.x - 0.5f;
        thi[p] = c.y + 0.5f;  tlo[p] = c.y - 0.5f;
    }
    int acc = 0;
    #pragma unroll
    for (int wr = 0; wr < RP + PAD; ++wr) {
        const float2* row = sm + (rg * RP + wr) * LW + tx;
        float2 v[9];
        #pragma unroll
        for (int j = 0; j < 9; ++j) v[j] = row[j];
        #pragma unroll
        for (int p = 0; p < RP; ++p) {
            int dh = wr - p;
            if (dh == 0) {
                #pragma unroll
                for (int j = 5; j <= 8; ++j)
                    tap_scalar(v[j].x, v[j].y, ehi[p], thi[p], elo[p], tlo[p], acc);
            } else if (dh >= 1 && dh <= PAD) {
                #pragma unroll
                for (int j = 0; j <= 8; ++j)
                    tap_scalar(v[j].x, v[j].y, ehi[p], thi[p], elo[p], tlo[p], acc);
            }
        }
    }
    if (tx == 0)
        atomicAdd(out, (float)acc * K_INT);   // acc is wave-uniform
}

// ============ edge: exactly 80 tiles/batch, guarded staging, pair weights ====
__global__ __launch_bounds__(256)
void edge_kernel(const float* __restrict__ disp0,
                 const float* __restrict__ im,
                 const float* __restrict__ pattern,
                 float* __restrict__ out)
{
    __shared__ float2 sm[LHW];

    const int t = blockIdx.x;        // 0..79
    int bx, by;
    if (t < 20) { by = (t >= 10) ? (GY - 1) : 0; bx = t % 10; }
    else        { int s = t - 20; bx = (s & 1) * (GX - 1); by = 1 + (s >> 1); }
    const int b  = blockIdx.y;
    const int tx = threadIdx.x, rg = threadIdx.y;
    const int tid = rg * 64 + tx;

    const float* db = disp0 + (size_t)b * HW;
    const float* ib = im    + (size_t)b * HW;
    float* proj = out + 1 + (size_t)b * HW;

    const int gh0 = by * HT;
    const int gw0 = bx * WT - PAD;

    #pragma unroll
    for (int it = 0; it < NIT; ++it) {
        int i = tid + it * 256;
        if (i < LHW) {
            int lh = i / LW, lw = i - lh * LW;
            int gh = gh0 + lh, gw = gw0 + lw;
            float ev = HALO, tv = HALO;
            if ((gh < HH) & (gw >= 0) & (gw < WW)) {
                int g = gh * WW + gw;
                float d = db[g];
                float x = fminf(fmaxf((float)gw - d, 0.0f), (float)(WW - 1));
                int   x0 = (int)x;
                int   x1 = min(x0 + 1, WW - 1);
                float w  = x - (float)x0;
                const float* pr = pattern + gh * WW;
                float p0 = (pr[x0] + pr[HW + x0] + pr[2*HW + x0]) * (1.0f/3.0f);
                float p1 = (pr[x1] + pr[HW + x1] + pr[2*HW + x1]) * (1.0f/3.0f);
                ev = p0 * (1.0f - w) + p1 * w;
                tv = ib[g];
                if ((lh < HT) & (lw >= PAD) & (lw < PAD + WT))
                    proj[g] = ev;
            }
            sm[i] = make_float2(ev, tv);
        }
    }
    __syncthreads();

    float invcw[9];
    const int w0 = bx * WT + tx;
    #pragma unroll
    for (int j = 0; j < 9; ++j) {
        int c  = w0 + j - PAD;                  // may be OOB (cw>=1; tap c=0 there)
        int cw = min(PAD, WW - 1 - c) + min(PAD, c) + 1;
        invcw[j] = fast_rcp((float)cw);
    }

    float ehi[RP], elo[RP], thi[RP], tlo[RP], wp[RP], facc[RP];
    int iacc[RP];
    #pragma unroll
    for (int p = 0; p < RP; ++p) {
        float2 c = sm[(rg * RP + p) * LW + tx + PAD];
        ehi[p] = c.x + 0.5f;  elo[p] = c.x - 0.5f;
        thi[p] = c.y + 0.5f;  tlo[p] = c.y - 0.5f;
        int r  = by * HT + rg * RP + p;
        int ch = min(PAD, HH - 1 - r) + min(PAD, r) + 1;
        wp[p]  = fast_rcp((float)ch) * invcw[PAD];   // center's own 1/count
        facc[p] = 0.0f;
        iacc[p] = 0;
    }

    #pragma unroll
    for (int wr = 0; wr < RP + PAD; ++wr) {
        int r  = by * HT + rg * RP + wr;        // may exceed HH-1 (tap c=0 there)
        int ch = min(PAD, HH - 1 - r) + min(PAD, r) + 1;
        float rowinv = fast_rcp((float)ch);

        const float2* row = sm + (rg * RP + wr) * LW + tx;
        float2 v[9];
        #pragma unroll
        for (int j = 0; j < 9; ++j) v[j] = row[j];

        #pragma unroll
        for (int p = 0; p < RP; ++p) {
            const bool d0 = (p == wr);
            if (p <= wr && p >= wr - PAD) {
                #pragma unroll
                for (int j = 0; j <= 8; ++j) {
                    if (d0 && j <= 4) continue;   // dh==0: forward cols only
                    int bh = (int)((v[j].x > ehi[p]) != (v[j].y > thi[p]));
                    int bl = (int)((v[j].x < elo[p]) != (v[j].y < tlo[p]));
                    int c  = bh + bl;
                    facc[p] = fmaf((float)c, rowinv * invcw[j], facc[p]);
                    iacc[p] += c;
                }
            }
        }
    }
    float tsum = 0.0f;
    #pragma unroll
    for (int p = 0; p < RP; ++p)
        tsum += facc[p] + wp[p] * (float)iacc[p];

    #pragma unroll
    for (int off = 32; off > 0; off >>= 1)
        tsum += __shfl_down(tsum, off, 64);
    if (tx == 0)
        atomicAdd(out, tsum * INV_N);
}

extern "C" void kernel_launch(void* const* d_in, const int* in_sizes, int n_in,
                              void* d_out, int out_size, void* d_ws, size_t ws_size,
                              hipStream_t stream) {
    const float* disp0   = (const float*)d_in[0];
    const float* im      = (const float*)d_in[1];
    const float* pattern = (const float*)d_in[2];
    float* out = (float*)d_out;

    // NO d_ws, NO memset: R1 (no-ws, no-memset) showed ~3us graph overhead vs
    // ~64us for every ws/memset structure (R3,5,7,9,10).
    zero_kernel<<<1, 1, 0, stream>>>(out);

    dim3 block(64, 4);
    dim3 gridI(GX - 2, GY - 2, BB);       // 8 x 30 x 16 interior tiles
    interior_kernel<<<gridI, block, 0, stream>>>(disp0, im, pattern, out);

    dim3 gridE(80, BB);                   // exactly the 80 edge tiles per batch
    edge_kernel<<<gridE, block, 0, stream>>>(disp0, im, pattern, out);
}